// Round 4
// baseline (192.789 us; speedup 1.0000x reference)
//
#include <hip/hip_runtime.h>
#include <hip/hip_cooperative_groups.h>

namespace cg = cooperative_groups;

#define N1 4096
#define N2 8192
#define FDIM 256
#define HDIM 128
#define OUTD 128
#define NBLK 1024

typedef float fx4 __attribute__((ext_vector_type(4)));

// mish(x) = x * tanh(softplus(x)) = x * ((1+e^x)^2 - 1) / ((1+e^x)^2 + 1)
// division via raw v_rcp_f32 (~1 ulp) — threshold is 9.5e-2, noise is ~1e-6.
__device__ __forceinline__ float mishf(float x) {
    float xc = fminf(x, 30.0f);          // tanh(softplus(x)) == 1.0f beyond this
    float e = __expf(xc);
    float w = 1.0f + e;
    float w2 = w * w;
    return x * (w2 - 1.0f) * __builtin_amdgcn_rcpf(w2 + 1.0f);
}

__global__ __launch_bounds__(256, 4) void fused_kernel(
    const float* __restrict__ m,  const float* __restrict__ m1,
    const float* __restrict__ m2, const float* __restrict__ m_h,
    const float* __restrict__ d,  const float* __restrict__ d1,
    const float* __restrict__ d2, const float* __restrict__ d_h,
    const float* __restrict__ w_m, const float* __restrict__ w_d,
    const float* __restrict__ a_m, const float* __restrict__ a_d,
    const float* __restrict__ a,
    float* __restrict__ ws,          // v[512] | xy[12288]
    fx4* __restrict__ out)
{
    cg::grid_group grid = cg::this_grid();
    float* v  = ws;
    float* xy = ws + 512;

    const int tid  = threadIdx.x;
    const int lane = tid & 63;
    const int gw   = (blockIdx.x << 2) + (tid >> 6);   // global wave id
    const int nw   = gridDim.x << 2;                   // total waves

    // ---- Phase A: v[c] = dot(w[c,:], a-slice)  (one wave per c) ----
    if (gw < 512) {
        const int c = gw;
        const float* wr = (c < 256) ? (w_m + c * OUTD) : (w_d + (c - 256) * OUTD);
        const float* av = (c < 256) ? a : (a + 2 * OUTD);
        float2 wv = ((const float2*)wr)[lane];
        float2 aa = ((const float2*)av)[lane];
        float s = wv.x * aa.x + wv.y * aa.y;
        #pragma unroll
        for (int off = 32; off > 0; off >>= 1) s += __shfl_down(s, off, 64);
        if (lane == 0) v[c] = s;
    }
    grid.sync();

    // ---- Phase B: one wave per row of x (rows < N1) / y (rows >= N1) ----
    for (int row = gw; row < N1 + N2; row += nw) {
        const float *pm, *pm1, *pm2, *ph, *pa, *pv;
        float c0, c1, c2;
        int r;
        if (row < N1) {
            r = row;
            pm = m; pm1 = m1; pm2 = m2; ph = m_h;
            pa = a + OUTD;                    // a1[128:256]
            pv = v;
            c0 = a_m[0]; c1 = a_m[1]; c2 = a_m[2];
        } else {
            r = row - N1;
            pm = d; pm1 = d1; pm2 = d2; ph = d_h;
            pa = a + 2 * OUTD + HDIM;         // a2[128:256] = a[384:512]
            pv = v + 256;
            c0 = a_d[0]; c1 = a_d[1]; c2 = a_d[2];
        }

        fx4 v0 = ((const fx4*)(pm  + (size_t)r * FDIM))[lane];
        fx4 v1 = ((const fx4*)(pm1 + (size_t)r * FDIM))[lane];
        fx4 v2 = ((const fx4*)(pm2 + (size_t)r * FDIM))[lane];
        fx4 vv = ((const fx4*)pv)[lane];

        float val = (c0 * v0.x + c1 * v1.x + c2 * v2.x) * vv.x
                  + (c0 * v0.y + c1 * v1.y + c2 * v2.y) * vv.y
                  + (c0 * v0.z + c1 * v1.z + c2 * v2.z) * vv.z
                  + (c0 * v0.w + c1 * v1.w + c2 * v2.w) * vv.w;

        if (lane < 32) {                      // 128 H-cols = 32 lanes x float4
            fx4 hv = ((const fx4*)(ph + (size_t)r * HDIM))[lane];
            fx4 av = ((const fx4*)pa)[lane];
            val += hv.x * av.x + hv.y * av.y + hv.z * av.z + hv.w * av.w;
        }

        #pragma unroll
        for (int off = 32; off > 0; off >>= 1) val += __shfl_down(val, off, 64);
        if (lane == 0) xy[row] = val;
    }
    grid.sync();

    // ---- Phase C: s[i,j] = mish(x[i] + y[j]), fx4 NT stores ----
    const float* x = xy;
    const float* y = xy + N1;
    const fx4* y4 = (const fx4*)y;
    const unsigned total  = (unsigned)N1 * (N2 / 4);   // 8,388,608 fx4
    const unsigned stride = gridDim.x << 8;
    for (unsigned vi = (blockIdx.x << 8) + (unsigned)tid; vi < total; vi += stride) {
        unsigned i  = vi >> 11;                        // 2048 fx4 per row
        unsigned j4 = vi & 2047;
        float xi = x[i];
        fx4 yv = y4[j4];
        fx4 r;
        r.x = mishf(xi + yv.x);
        r.y = mishf(xi + yv.y);
        r.z = mishf(xi + yv.z);
        r.w = mishf(xi + yv.w);
        __builtin_nontemporal_store(r, &out[vi]);
    }
}

extern "C" void kernel_launch(void* const* d_in, const int* in_sizes, int n_in,
                              void* d_out, int out_size, void* d_ws, size_t ws_size,
                              hipStream_t stream) {
    const float* m   = (const float*)d_in[0];
    const float* m1  = (const float*)d_in[1];
    const float* m2  = (const float*)d_in[2];
    const float* m_h = (const float*)d_in[3];
    const float* d   = (const float*)d_in[4];
    const float* d1  = (const float*)d_in[5];
    const float* d2  = (const float*)d_in[6];
    const float* d_h = (const float*)d_in[7];
    const float* w_m = (const float*)d_in[8];
    const float* w_d = (const float*)d_in[9];
    const float* a_m = (const float*)d_in[10];
    const float* a_d = (const float*)d_in[11];
    const float* a   = (const float*)d_in[12];

    float* wsf = (float*)d_ws;
    fx4*   out = (fx4*)d_out;

    void* args[] = {
        (void*)&m, (void*)&m1, (void*)&m2, (void*)&m_h,
        (void*)&d, (void*)&d1, (void*)&d2, (void*)&d_h,
        (void*)&w_m, (void*)&w_d, (void*)&a_m, (void*)&a_d, (void*)&a,
        (void*)&wsf, (void*)&out
    };
    hipLaunchCooperativeKernel((void*)fused_kernel, dim3(NBLK), dim3(256),
                               args, 0, stream);
}

// Round 5
// 47.757 us; speedup vs baseline: 4.0369x; 4.0369x over previous
//
#include <hip/hip_runtime.h>

#define N1 4096
#define N2 8192
#define FDIM 256
#define HDIM 128
#define OUTD 128

typedef float fx4 __attribute__((ext_vector_type(4)));

// mish(x) = x * tanh(softplus(x)) = x * ((1+e^x)^2 - 1) / ((1+e^x)^2 + 1)
// division via raw v_rcp_f32 (~1 ulp) — threshold is 9.5e-2.
__device__ __forceinline__ float mishf(float x) {
    float xc = fminf(x, 30.0f);          // tanh(softplus(x)) == 1.0f beyond this
    float e = __expf(xc);
    float w = 1.0f + e;
    float w2 = w * w;
    return x * (w2 - 1.0f) * __builtin_amdgcn_rcpf(w2 + 1.0f);
}

// One block, 512 threads: v_m[c] = dot(w_m[c,:], a[0:128]);  v_d[c] = dot(w_d[c,:], a[256:384])
__global__ void compute_v_kernel(const float* __restrict__ w_m,
                                 const float* __restrict__ w_d,
                                 const float* __restrict__ a,
                                 float* __restrict__ v /* 512 floats: v_m | v_d */) {
    int t = threadIdx.x;
    const float* wr;
    const float* av;
    if (t < 256) {
        wr = w_m + t * OUTD;
        av = a;                 // a1[:128]
    } else {
        wr = w_d + (t - 256) * OUTD;
        av = a + 2 * OUTD;      // a2[:128] = a[256:384]
    }
    float s = 0.f;
    #pragma unroll 8
    for (int o = 0; o < OUTD; ++o) s += wr[o] * av[o];
    v[t] = s;
}

// One wave (64 lanes) per row. Lane l handles cols [4l, 4l+4) via float4.
// x[i] = sum_c (am0*m+am1*m1+am2*m2)[i,c]*v_m[c] + sum_h m_h[i,h]*a[128+h]
__global__ void compute_xy_kernel(const float* __restrict__ m,  const float* __restrict__ m1,
                                  const float* __restrict__ m2, const float* __restrict__ m_h,
                                  const float* __restrict__ d,  const float* __restrict__ d1,
                                  const float* __restrict__ d2, const float* __restrict__ d_h,
                                  const float* __restrict__ a_m, const float* __restrict__ a_d,
                                  const float* __restrict__ a,
                                  const float* __restrict__ v,
                                  float* __restrict__ xy /* x[0..N1) then y[N1..N1+N2) */) {
    int gtid = blockIdx.x * blockDim.x + threadIdx.x;
    int row  = gtid >> 6;                 // one wave per row
    int lane = threadIdx.x & 63;

    const float *pm, *pm1, *pm2, *ph, *pa, *pv;
    float c0, c1, c2;
    int r;
    if (row < N1) {
        r = row;
        pm = m; pm1 = m1; pm2 = m2; ph = m_h;
        pa = a + OUTD;                    // a1[128:256]
        pv = v;
        c0 = a_m[0]; c1 = a_m[1]; c2 = a_m[2];
    } else {
        r = row - N1;
        pm = d; pm1 = d1; pm2 = d2; ph = d_h;
        pa = a + 2 * OUTD + HDIM;         // a2[128:256] = a[384:512]
        pv = v + 256;
        c0 = a_d[0]; c1 = a_d[1]; c2 = a_d[2];
    }

    fx4 v0 = ((const fx4*)(pm  + (size_t)r * FDIM))[lane];
    fx4 v1 = ((const fx4*)(pm1 + (size_t)r * FDIM))[lane];
    fx4 v2 = ((const fx4*)(pm2 + (size_t)r * FDIM))[lane];
    fx4 vv = ((const fx4*)pv)[lane];

    float val = (c0 * v0.x + c1 * v1.x + c2 * v2.x) * vv.x
              + (c0 * v0.y + c1 * v1.y + c2 * v2.y) * vv.y
              + (c0 * v0.z + c1 * v1.z + c2 * v2.z) * vv.z
              + (c0 * v0.w + c1 * v1.w + c2 * v2.w) * vv.w;

    if (lane < 32) {                      // 128 H-cols = 32 lanes x float4
        fx4 hv = ((const fx4*)(ph + (size_t)r * HDIM))[lane];
        fx4 av = ((const fx4*)pa)[lane];
        val += hv.x * av.x + hv.y * av.y + hv.z * av.z + hv.w * av.w;
    }

    #pragma unroll
    for (int off = 32; off > 0; off >>= 1) val += __shfl_down(val, off, 64);
    if (lane == 0) xy[row] = val;
}

// s[i,j] = mish(x[i] + y[j]). Max-TLP version: 65536 waves, each wave writes
// 128 consecutive fx4 (2 KB) via two coalesced NT dwordx4 stores, no loop.
// Store BW is outstanding-request-bound -> more waves, fewer serial stores each.
__global__ void mish_bcast_kernel(const float* __restrict__ x,
                                  const float* __restrict__ y,
                                  fx4* __restrict__ out) {
    const unsigned gtid = blockIdx.x * blockDim.x + threadIdx.x;
    const unsigned wid  = gtid >> 6;
    const unsigned lane = threadIdx.x & 63;
    const unsigned base = wid << 7;            // 128 fx4 per wave
    const unsigned vi0  = base + lane;
    const unsigned vi1  = vi0 + 64;
    const unsigned i    = base >> 11;          // 2048 fx4 per row; wave-uniform
    const fx4* y4 = (const fx4*)y;

    float xi = x[i];
    fx4 y0 = y4[vi0 & 2047];
    fx4 y1 = y4[vi1 & 2047];

    fx4 r0, r1;
    r0.x = mishf(xi + y0.x);
    r0.y = mishf(xi + y0.y);
    r0.z = mishf(xi + y0.z);
    r0.w = mishf(xi + y0.w);
    r1.x = mishf(xi + y1.x);
    r1.y = mishf(xi + y1.y);
    r1.z = mishf(xi + y1.z);
    r1.w = mishf(xi + y1.w);

    __builtin_nontemporal_store(r0, &out[vi0]);
    __builtin_nontemporal_store(r1, &out[vi1]);
}

extern "C" void kernel_launch(void* const* d_in, const int* in_sizes, int n_in,
                              void* d_out, int out_size, void* d_ws, size_t ws_size,
                              hipStream_t stream) {
    const float* m   = (const float*)d_in[0];
    const float* m1  = (const float*)d_in[1];
    const float* m2  = (const float*)d_in[2];
    const float* m_h = (const float*)d_in[3];
    const float* d   = (const float*)d_in[4];
    const float* d1  = (const float*)d_in[5];
    const float* d2  = (const float*)d_in[6];
    const float* d_h = (const float*)d_in[7];
    const float* w_m = (const float*)d_in[8];
    const float* w_d = (const float*)d_in[9];
    const float* a_m = (const float*)d_in[10];
    const float* a_d = (const float*)d_in[11];
    const float* a   = (const float*)d_in[12];

    float* wsf = (float*)d_ws;
    float* v  = wsf;          // 512 floats
    float* xy = wsf + 512;    // 4096 + 8192 floats

    compute_v_kernel<<<1, 512, 0, stream>>>(w_m, w_d, a, v);
    // one wave per row: (N1+N2) waves = 12288 -> 3072 blocks of 256 threads
    compute_xy_kernel<<<(N1 + N2) / 4, 256, 0, stream>>>(m, m1, m2, m_h, d, d1, d2, d_h,
                                                         a_m, a_d, a, v, xy);
    // 8,388,608 fx4 / 128 per wave = 65536 waves = 16384 blocks
    mish_bcast_kernel<<<16384, 256, 0, stream>>>(xy, xy + N1, (fx4*)d_out);
}

// Round 6
// 45.954 us; speedup vs baseline: 4.1952x; 1.0392x over previous
//
#include <hip/hip_runtime.h>

#define N1 4096
#define N2 8192
#define FDIM 256
#define HDIM 128
#define OUTD 128

typedef float fx4 __attribute__((ext_vector_type(4)));

// mish(x) = x * tanh(softplus(x)) = x * ((1+e^x)^2 - 1) / ((1+e^x)^2 + 1)
// division via raw v_rcp_f32 (~1 ulp) — threshold is 9.5e-2.
__device__ __forceinline__ float mishf(float x) {
    float xc = fminf(x, 30.0f);          // tanh(softplus(x)) == 1.0f beyond this
    float e = __expf(xc);
    float w = 1.0f + e;
    float w2 = w * w;
    return x * (w2 - 1.0f) * __builtin_amdgcn_rcpf(w2 + 1.0f);
}

// One block, 512 threads: v_m[c] = dot(w_m[c,:], a[0:128]);  v_d[c] = dot(w_d[c,:], a[256:384])
__global__ void compute_v_kernel(const float* __restrict__ w_m,
                                 const float* __restrict__ w_d,
                                 const float* __restrict__ a,
                                 float* __restrict__ v /* 512 floats: v_m | v_d */) {
    int t = threadIdx.x;
    const float* wr;
    const float* av;
    if (t < 256) {
        wr = w_m + t * OUTD;
        av = a;                 // a1[:128]
    } else {
        wr = w_d + (t - 256) * OUTD;
        av = a + 2 * OUTD;      // a2[:128] = a[256:384]
    }
    float s = 0.f;
    #pragma unroll 8
    for (int o = 0; o < OUTD; ++o) s += wr[o] * av[o];
    v[t] = s;
}

// One wave (64 lanes) per row. Lane l handles cols [4l, 4l+4) via float4.
// x[i] = sum_c (am0*m+am1*m1+am2*m2)[i,c]*v_m[c] + sum_h m_h[i,h]*a[128+h]
__global__ void compute_xy_kernel(const float* __restrict__ m,  const float* __restrict__ m1,
                                  const float* __restrict__ m2, const float* __restrict__ m_h,
                                  const float* __restrict__ d,  const float* __restrict__ d1,
                                  const float* __restrict__ d2, const float* __restrict__ d_h,
                                  const float* __restrict__ a_m, const float* __restrict__ a_d,
                                  const float* __restrict__ a,
                                  const float* __restrict__ v,
                                  float* __restrict__ xy /* x[0..N1) then y[N1..N1+N2) */) {
    int gtid = blockIdx.x * blockDim.x + threadIdx.x;
    int row  = gtid >> 6;                 // one wave per row
    int lane = threadIdx.x & 63;

    const float *pm, *pm1, *pm2, *ph, *pa, *pv;
    float c0, c1, c2;
    int r;
    if (row < N1) {
        r = row;
        pm = m; pm1 = m1; pm2 = m2; ph = m_h;
        pa = a + OUTD;                    // a1[128:256]
        pv = v;
        c0 = a_m[0]; c1 = a_m[1]; c2 = a_m[2];
    } else {
        r = row - N1;
        pm = d; pm1 = d1; pm2 = d2; ph = d_h;
        pa = a + 2 * OUTD + HDIM;         // a2[128:256] = a[384:512]
        pv = v + 256;
        c0 = a_d[0]; c1 = a_d[1]; c2 = a_d[2];
    }

    fx4 v0 = ((const fx4*)(pm  + (size_t)r * FDIM))[lane];
    fx4 v1 = ((const fx4*)(pm1 + (size_t)r * FDIM))[lane];
    fx4 v2 = ((const fx4*)(pm2 + (size_t)r * FDIM))[lane];
    fx4 vv = ((const fx4*)pv)[lane];

    float val = (c0 * v0.x + c1 * v1.x + c2 * v2.x) * vv.x
              + (c0 * v0.y + c1 * v1.y + c2 * v2.y) * vv.y
              + (c0 * v0.z + c1 * v1.z + c2 * v2.z) * vv.z
              + (c0 * v0.w + c1 * v1.w + c2 * v2.w) * vv.w;

    if (lane < 32) {                      // 128 H-cols = 32 lanes x float4
        fx4 hv = ((const fx4*)(ph + (size_t)r * HDIM))[lane];
        fx4 av = ((const fx4*)pa)[lane];
        val += hv.x * av.x + hv.y * av.y + hv.z * av.z + hv.w * av.w;
    }

    #pragma unroll
    for (int off = 32; off > 0; off >>= 1) val += __shfl_down(val, off, 64);
    if (lane == 0) xy[row] = val;
}

// s[i,j] = mish(x[i] + y[j]). 65536 waves, each wave writes 128 consecutive
// fx4 (2 KB) via two coalesced dwordx4 stores. PLAIN stores (through-L2
// writeback, same path as the 7.15 TB/s fillBuffer) — A/B vs R5's NT stores.
__global__ void mish_bcast_kernel(const float* __restrict__ x,
                                  const float* __restrict__ y,
                                  fx4* __restrict__ out) {
    const unsigned gtid = blockIdx.x * blockDim.x + threadIdx.x;
    const unsigned wid  = gtid >> 6;
    const unsigned lane = threadIdx.x & 63;
    const unsigned base = wid << 7;            // 128 fx4 per wave
    const unsigned vi0  = base + lane;
    const unsigned vi1  = vi0 + 64;
    const unsigned i    = base >> 11;          // 2048 fx4 per row; wave-uniform
    const fx4* y4 = (const fx4*)y;

    float xi = x[i];
    fx4 y0 = y4[vi0 & 2047];
    fx4 y1 = y4[vi1 & 2047];

    fx4 r0, r1;
    r0.x = mishf(xi + y0.x);
    r0.y = mishf(xi + y0.y);
    r0.z = mishf(xi + y0.z);
    r0.w = mishf(xi + y0.w);
    r1.x = mishf(xi + y1.x);
    r1.y = mishf(xi + y1.y);
    r1.z = mishf(xi + y1.z);
    r1.w = mishf(xi + y1.w);

    out[vi0] = r0;
    out[vi1] = r1;
}

extern "C" void kernel_launch(void* const* d_in, const int* in_sizes, int n_in,
                              void* d_out, int out_size, void* d_ws, size_t ws_size,
                              hipStream_t stream) {
    const float* m   = (const float*)d_in[0];
    const float* m1  = (const float*)d_in[1];
    const float* m2  = (const float*)d_in[2];
    const float* m_h = (const float*)d_in[3];
    const float* d   = (const float*)d_in[4];
    const float* d1  = (const float*)d_in[5];
    const float* d2  = (const float*)d_in[6];
    const float* d_h = (const float*)d_in[7];
    const float* w_m = (const float*)d_in[8];
    const float* w_d = (const float*)d_in[9];
    const float* a_m = (const float*)d_in[10];
    const float* a_d = (const float*)d_in[11];
    const float* a   = (const float*)d_in[12];

    float* wsf = (float*)d_ws;
    float* v  = wsf;          // 512 floats
    float* xy = wsf + 512;    // 4096 + 8192 floats

    compute_v_kernel<<<1, 512, 0, stream>>>(w_m, w_d, a, v);
    // one wave per row: (N1+N2) waves = 12288 -> 3072 blocks of 256 threads
    compute_xy_kernel<<<(N1 + N2) / 4, 256, 0, stream>>>(m, m1, m2, m_h, d, d1, d2, d_h,
                                                         a_m, a_d, a, v, xy);
    // 8,388,608 fx4 / 128 per wave = 65536 waves = 16384 blocks
    mish_bcast_kernel<<<16384, 256, 0, stream>>>(xy, xy + N1, (fx4*)d_out);
}

// Round 7
// 39.106 us; speedup vs baseline: 4.9299x; 1.1751x over previous
//
#include <hip/hip_runtime.h>

#define N1 4096
#define N2 8192
#define FDIM 256
#define HDIM 128
#define OUTD 128

typedef float fx4 __attribute__((ext_vector_type(4)));

// mish(x) = x * tanh(softplus(x)) = x * ((1+e^x)^2 - 1) / ((1+e^x)^2 + 1)
// division via raw v_rcp_f32 (~1 ulp) — threshold is 9.5e-2.
__device__ __forceinline__ float mishf(float x) {
    float xc = fminf(x, 30.0f);          // tanh(softplus(x)) == 1.0f beyond this
    float e = __expf(xc);
    float w = 1.0f + e;
    float w2 = w * w;
    return x * (w2 - 1.0f) * __builtin_amdgcn_rcpf(w2 + 1.0f);
}

// 512 waves, one per output element: v[c] = dot(w[c,:], a-slice).
// Spread across 128 blocks so the 256 KB of w reads use many CUs' HBM share.
__global__ void compute_v_kernel(const float* __restrict__ w_m,
                                 const float* __restrict__ w_d,
                                 const float* __restrict__ a,
                                 float* __restrict__ v /* 512 floats: v_m | v_d */) {
    int wave = (blockIdx.x << 2) + (threadIdx.x >> 6);   // 0..511
    int lane = threadIdx.x & 63;
    const float* wr = (wave < 256) ? (w_m + wave * OUTD) : (w_d + (wave - 256) * OUTD);
    const float* av = (wave < 256) ? a : (a + 2 * OUTD);
    float2 wv = ((const float2*)wr)[lane];
    float2 aa = ((const float2*)av)[lane];
    float s = wv.x * aa.x + wv.y * aa.y;
    #pragma unroll
    for (int off = 32; off > 0; off >>= 1) s += __shfl_down(s, off, 64);
    if (lane == 0) v[wave] = s;
}

// One wave (64 lanes) per row. Lane l handles cols [4l, 4l+4) via float4.
// x[i] = sum_c (am0*m+am1*m1+am2*m2)[i,c]*v_m[c] + sum_h m_h[i,h]*a[128+h]
__global__ void compute_xy_kernel(const float* __restrict__ m,  const float* __restrict__ m1,
                                  const float* __restrict__ m2, const float* __restrict__ m_h,
                                  const float* __restrict__ d,  const float* __restrict__ d1,
                                  const float* __restrict__ d2, const float* __restrict__ d_h,
                                  const float* __restrict__ a_m, const float* __restrict__ a_d,
                                  const float* __restrict__ a,
                                  const float* __restrict__ v,
                                  float* __restrict__ xy /* x[0..N1) then y[N1..N1+N2) */) {
    int gtid = blockIdx.x * blockDim.x + threadIdx.x;
    int row  = gtid >> 6;                 // one wave per row
    int lane = threadIdx.x & 63;

    const float *pm, *pm1, *pm2, *ph, *pa, *pv;
    float c0, c1, c2;
    int r;
    if (row < N1) {
        r = row;
        pm = m; pm1 = m1; pm2 = m2; ph = m_h;
        pa = a + OUTD;                    // a1[128:256]
        pv = v;
        c0 = a_m[0]; c1 = a_m[1]; c2 = a_m[2];
    } else {
        r = row - N1;
        pm = d; pm1 = d1; pm2 = d2; ph = d_h;
        pa = a + 2 * OUTD + HDIM;         // a2[128:256] = a[384:512]
        pv = v + 256;
        c0 = a_d[0]; c1 = a_d[1]; c2 = a_d[2];
    }

    fx4 v0 = ((const fx4*)(pm  + (size_t)r * FDIM))[lane];
    fx4 v1 = ((const fx4*)(pm1 + (size_t)r * FDIM))[lane];
    fx4 v2 = ((const fx4*)(pm2 + (size_t)r * FDIM))[lane];
    fx4 vv = ((const fx4*)pv)[lane];

    float val = (c0 * v0.x + c1 * v1.x + c2 * v2.x) * vv.x
              + (c0 * v0.y + c1 * v1.y + c2 * v2.y) * vv.y
              + (c0 * v0.z + c1 * v1.z + c2 * v2.z) * vv.z
              + (c0 * v0.w + c1 * v1.w + c2 * v2.w) * vv.w;

    if (lane < 32) {                      // 128 H-cols = 32 lanes x float4
        fx4 hv = ((const fx4*)(ph + (size_t)r * HDIM))[lane];
        fx4 av = ((const fx4*)pa)[lane];
        val += hv.x * av.x + hv.y * av.y + hv.z * av.z + hv.w * av.w;
    }

    #pragma unroll
    for (int off = 32; off > 0; off >>= 1) val += __shfl_down(val, off, 64);
    if (lane == 0) xy[row] = val;
}

// s[i,j] = mish(x[i] + y[j]) — streaming-store version.
// Each wave owns a 256-float column window (1 fx4/lane, loaded ONCE) across
// 8 consecutive rows: 8 back-to-back 1 KB coalesced stores, zero loads in
// the store stream (fillBuffer-like). 16384 waves = 4096 blocks.
__global__ void mish_bcast_kernel(const float* __restrict__ x,
                                  const float* __restrict__ y,
                                  fx4* __restrict__ out) {
    const unsigned gtid = blockIdx.x * blockDim.x + threadIdx.x;
    const unsigned wid  = gtid >> 6;           // 0..16383
    const unsigned lane = threadIdx.x & 63;
    const unsigned rg   = wid >> 5;            // row-group: 8 rows each
    const unsigned cg   = wid & 31;            // col-group: 64 fx4 each
    const unsigned col4 = (cg << 6) + lane;    // fx4 column index, wave-uniform per store

    fx4 yv = ((const fx4*)y)[col4];            // this wave's y slice (once)
    // 8 row scalars, loaded once (broadcast; 32B-aligned)
    fx4 xa = ((const fx4*)(x + (rg << 3)))[0];
    fx4 xb = ((const fx4*)(x + (rg << 3)))[1];
    float xs[8] = {xa.x, xa.y, xa.z, xa.w, xb.x, xb.y, xb.z, xb.w};

    fx4* o = out + ((size_t)(rg << 3) << 11) + col4;   // row (rg*8), 2048 fx4/row
    #pragma unroll
    for (int rr = 0; rr < 8; ++rr) {
        float xi = xs[rr];
        fx4 r;
        r.x = mishf(xi + yv.x);
        r.y = mishf(xi + yv.y);
        r.z = mishf(xi + yv.z);
        r.w = mishf(xi + yv.w);
        o[(size_t)rr << 11] = r;
    }
}

extern "C" void kernel_launch(void* const* d_in, const int* in_sizes, int n_in,
                              void* d_out, int out_size, void* d_ws, size_t ws_size,
                              hipStream_t stream) {
    const float* m   = (const float*)d_in[0];
    const float* m1  = (const float*)d_in[1];
    const float* m2  = (const float*)d_in[2];
    const float* m_h = (const float*)d_in[3];
    const float* d   = (const float*)d_in[4];
    const float* d1  = (const float*)d_in[5];
    const float* d2  = (const float*)d_in[6];
    const float* d_h = (const float*)d_in[7];
    const float* w_m = (const float*)d_in[8];
    const float* w_d = (const float*)d_in[9];
    const float* a_m = (const float*)d_in[10];
    const float* a_d = (const float*)d_in[11];
    const float* a   = (const float*)d_in[12];

    float* wsf = (float*)d_ws;
    float* v  = wsf;          // 512 floats
    float* xy = wsf + 512;    // 4096 + 8192 floats

    compute_v_kernel<<<128, 256, 0, stream>>>(w_m, w_d, a, v);
    // one wave per row: (N1+N2) waves = 12288 -> 3072 blocks of 256 threads
    compute_xy_kernel<<<(N1 + N2) / 4, 256, 0, stream>>>(m, m1, m2, m_h, d, d1, d2, d_h,
                                                         a_m, a_d, a, v, xy);
    // 16384 waves: 512 row-groups (8 rows) x 32 col-groups (256 floats)
    mish_bcast_kernel<<<4096, 256, 0, stream>>>(xy, xy + N1, (fx4*)d_out);
}